// Round 1
// baseline (790.664 us; speedup 1.0000x reference)
//
#include <hip/hip_runtime.h>

#define TT 1024
#define LOG2E 1.4426950408889634f
#define LN2   0.6931471805599453f

typedef __attribute__((ext_vector_type(8))) short short8;
typedef __attribute__((ext_vector_type(4))) float f32x4;

#if __has_builtin(__builtin_amdgcn_exp2f)
#define EXP2F(x) __builtin_amdgcn_exp2f(x)
#else
#define EXP2F(x) exp2f(x)
#endif
#if __has_builtin(__builtin_amdgcn_logf)
#define LOG2F(x) __builtin_amdgcn_logf(x)
#else
#define LOG2F(x) log2f(x)
#endif

// round-to-nearest-even float -> bf16 bits
__device__ inline short f2bf(float f) {
    union { float f; unsigned u; } v; v.f = f;
    unsigned r = v.u + 0x7fffu + ((v.u >> 16) & 1u);
    return (short)(r >> 16);
}

__device__ inline float fast_sigmoid(float x) {
    // 1/(1+e^-x) = rcp(1 + 2^(-x*log2e))
    float e = EXP2F(x * -LOG2E);
    return __builtin_amdgcn_rcpf(1.0f + e);
}
__device__ inline float fast_tanh(float x) {
    // tanh = 1 - 2/(e^(2x)+1)
    float e = EXP2F(x * (2.0f * LOG2E));
    return fmaf(-2.0f, __builtin_amdgcn_rcpf(e + 1.0f), 1.0f);
}

// One wave handles 16 batch elements (one 16x16 MFMA tile).
// Per timestep: gates[16b x 64g] = [h | x | pad](bf16) @ [W_hh^T ; W_ih^T](bf16) + bias(fp32 C-init)
// via 4x mfma_f32_16x16x32_bf16 (one per gate group i,f,g,o).
// C/D layout: col = lane&15 (hidden j), row = (lane>>4)*4 + reg (batch)  -> per-lane fp32 LSTM update.
// A layout:   m = lane&15 (batch),     k = (lane>>4)*8 + j               -> h re-enters via LDS transpose.
__global__ __launch_bounds__(256, 2)
void lstm_head_kernel(const float* __restrict__ x,
                      const float* __restrict__ W_ih,
                      const float* __restrict__ W_hh,
                      const float* __restrict__ b_ih,
                      const float* __restrict__ b_hh,
                      const float* __restrict__ W1,
                      const float* __restrict__ b1,
                      const float* __restrict__ W2,
                      const float* __restrict__ b2,
                      float* __restrict__ out)
{
    __shared__ short lds_h[4][16 * 24];   // per-wave h tile, [batch row][hid], pitch 24 bf16 = 48B (16B-aligned rows)
    __shared__ float lds_f[4][16 * 17];   // final h fp32 for the head, +1 pad

    const int tid  = threadIdx.x;
    const int wib  = tid >> 6;            // wave in block 0..3
    const int lane = tid & 63;
    const int n    = lane & 15;
    const int q    = lane >> 4;           // quadrant 0..3
    const int batch0 = (blockIdx.x * 4 + wib) * 16;

    short* hrow = lds_h[wib];

    // ---- B fragments (fixed weights) + fp32 bias, loaded once ----
    // B[k][col n]: k<16 -> W_hh[g*16+n][k]; k==16 -> W_ih[g*16+n]; else 0
    short8 bfrag[4];
    float bias[4];
    #pragma unroll
    for (int g = 0; g < 4; ++g) {
        const int row = g * 16 + n;
        short8 bf;
        #pragma unroll
        for (int j = 0; j < 8; ++j) {
            const int k = q * 8 + j;
            float w = 0.0f;
            if (k < 16)       w = W_hh[row * 16 + k];
            else if (k == 16) w = W_ih[row];
            bf[j] = f2bf(w);
        }
        bfrag[g] = bf;
        bias[g] = b_ih[row] + b_hh[row];
    }

    // zero initial h tile (all 64 lanes cover all 16x16 entries)
    #pragma unroll
    for (int r = 0; r < 4; ++r)
        hrow[(q * 4 + r) * 24 + n] = 0;

    float c[4]    = {0.f, 0.f, 0.f, 0.f};
    float hreg[4] = {0.f, 0.f, 0.f, 0.f};

    const float* xp = x + (size_t)(batch0 + n) * TT;   // only q==2 lanes consume

    for (int t4 = 0; t4 < TT; t4 += 4) {
        float4 xv = make_float4(0.f, 0.f, 0.f, 0.f);
        if (q == 2) xv = *(const float4*)(xp + t4);
        const float xs[4] = {xv.x, xv.y, xv.z, xv.w};

        #pragma unroll
        for (int s = 0; s < 4; ++s) {
            // ---- build A fragment ----
            short8 a = {0, 0, 0, 0, 0, 0, 0, 0};
            if (lane < 32) {
                // k = q*8..q*8+7 of h[batch m = n]
                a = *(const short8*)(hrow + n * 24 + q * 8);
            } else if (lane < 48) {
                a[0] = f2bf(xs[s]);                    // k==16 slot: x[b,t]
            }

            f32x4 acc0 = {bias[0], bias[0], bias[0], bias[0]};
            f32x4 acc1 = {bias[1], bias[1], bias[1], bias[1]};
            f32x4 acc2 = {bias[2], bias[2], bias[2], bias[2]};
            f32x4 acc3 = {bias[3], bias[3], bias[3], bias[3]};
            acc0 = __builtin_amdgcn_mfma_f32_16x16x32_bf16(a, bfrag[0], acc0, 0, 0, 0); // i
            acc1 = __builtin_amdgcn_mfma_f32_16x16x32_bf16(a, bfrag[1], acc1, 0, 0, 0); // f
            acc2 = __builtin_amdgcn_mfma_f32_16x16x32_bf16(a, bfrag[2], acc2, 0, 0, 0); // g
            acc3 = __builtin_amdgcn_mfma_f32_16x16x32_bf16(a, bfrag[3], acc3, 0, 0, 0); // o

            // ---- per-lane LSTM update: 4 batch rows, hidden j = n ----
            #pragma unroll
            for (int r = 0; r < 4; ++r) {
                float ig = fast_sigmoid(acc0[r]);
                float fg = fast_sigmoid(acc1[r]);
                float gg = fast_tanh(acc2[r]);
                float og = fast_sigmoid(acc3[r]);
                c[r] = fmaf(fg, c[r], ig * gg);
                float hv = og * fast_tanh(c[r]);
                hreg[r] = hv;
                hrow[(q * 4 + r) * 24 + n] = f2bf(hv);  // back to A-side layout via LDS
            }
        }
    }

    // ---- head: stage final h (fp32, exact) then 16 lanes do MLP + log_softmax ----
    float* fh = lds_f[wib];
    #pragma unroll
    for (int r = 0; r < 4; ++r)
        fh[(q * 4 + r) * 17 + n] = hreg[r];

    if (lane < 16) {
        const int b = batch0 + lane;
        float hv[16];
        #pragma unroll
        for (int j = 0; j < 16; ++j) hv[j] = fh[lane * 17 + j];

        float a1[32];
        #pragma unroll
        for (int u = 0; u < 32; ++u) {
            float s = b1[u];
            #pragma unroll
            for (int j = 0; j < 16; ++j) s = fmaf(W1[u * 16 + j], hv[j], s);
            a1[u] = fmaxf(s, 0.0f);
        }

        float z[6];
        float m = -1e30f;
        #pragma unroll
        for (int v = 0; v < 6; ++v) {
            float s = b2[v];
            #pragma unroll
            for (int u = 0; u < 32; ++u) s = fmaf(W2[v * 32 + u], a1[u], s);
            z[v] = s;
            m = fmaxf(m, s);
        }
        float se = 0.0f;
        #pragma unroll
        for (int v = 0; v < 6; ++v) se += EXP2F((z[v] - m) * LOG2E);
        const float lse = m + LOG2F(se) * LN2;
        #pragma unroll
        for (int v = 0; v < 6; ++v) out[b * 6 + v] = z[v] - lse;
    }
}

extern "C" void kernel_launch(void* const* d_in, const int* in_sizes, int n_in,
                              void* d_out, int out_size, void* d_ws, size_t ws_size,
                              hipStream_t stream) {
    const float* x    = (const float*)d_in[0];
    const float* W_ih = (const float*)d_in[1];
    const float* W_hh = (const float*)d_in[2];
    const float* b_ih = (const float*)d_in[3];
    const float* b_hh = (const float*)d_in[4];
    const float* W1   = (const float*)d_in[5];
    const float* b1   = (const float*)d_in[6];
    const float* W2   = (const float*)d_in[7];
    const float* b2   = (const float*)d_in[8];
    float* out = (float*)d_out;

    const int B = out_size / 6;          // 32768
    const int nblocks = B / 64;          // 64 batch per block (4 waves x 16)

    hipLaunchKernelGGL(lstm_head_kernel, dim3(nblocks), dim3(256), 0, stream,
                       x, W_ih, W_hh, b_ih, b_hh, W1, b1, W2, b2, out);
}

// Round 2
// 736.279 us; speedup vs baseline: 1.0739x; 1.0739x over previous
//
#include <hip/hip_runtime.h>

#define TT 1024
#define LOG2E 1.4426950408889634f
#define LN2   0.6931471805599453f

typedef __attribute__((ext_vector_type(4))) _Float16 half4;
typedef __attribute__((ext_vector_type(4))) float f32x4;

#if __has_builtin(__builtin_amdgcn_exp2f)
#define EXP2F(x) __builtin_amdgcn_exp2f(x)
#else
#define EXP2F(x) exp2f(x)
#endif
#if __has_builtin(__builtin_amdgcn_logf)
#define LOG2F(x) __builtin_amdgcn_logf(x)
#else
#define LOG2F(x) log2f(x)
#endif

__device__ inline float fast_sigmoid(float x) {
    float e = EXP2F(x * -LOG2E);
    return __builtin_amdgcn_rcpf(1.0f + e);
}
__device__ inline float fast_tanh(float x) {
    float e = EXP2F(x * (2.0f * LOG2E));
    return fmaf(-2.0f, __builtin_amdgcn_rcpf(e + 1.0f), 1.0f);
}

// Gates computed TRANSPOSED: G[gate_row][batch] = W_hh(16x16 per gate) @ h^T,
// one v_mfma_f32_16x16x16f16 per gate group.
//   A (weights, fixed):  A[m][k] = W_hh[g*16+m][k],  m=lane&15, k=(lane>>4)*4+i
//   B (h, per step):     B[k][n] = h[batch n][hid k], n=lane&15, k=(lane>>4)*4+i
//   C/D:                 col n = lane&15 (batch), row m = (lane>>4)*4+reg (gate row)
// KEY: D layout == B layout for this shape, so the updated h per lane converts
// directly into next step's B fragment (4x v_cvt_f16_f32) — no LDS, no shuffle.
// x*W_ih + b folds into the fp32 C-init (16 fma/lane/step).
__global__ __launch_bounds__(256, 2)
void lstm_head_kernel(const float* __restrict__ x,
                      const float* __restrict__ W_ih,
                      const float* __restrict__ W_hh,
                      const float* __restrict__ b_ih,
                      const float* __restrict__ b_hh,
                      const float* __restrict__ W1,
                      const float* __restrict__ b1,
                      const float* __restrict__ W2,
                      const float* __restrict__ b2,
                      float* __restrict__ out)
{
    __shared__ float lds_f[4][16 * 17];   // final h fp32 staging for the head

    const int tid  = threadIdx.x;
    const int wib  = tid >> 6;
    const int lane = tid & 63;
    const int n    = lane & 15;           // batch within tile (and gate-col m for A)
    const int q    = lane >> 4;           // quadrant
    const int batch0 = (blockIdx.x * 4 + wib) * 16;

    // ---- fixed per-lane constants ----
    half4 wfrag[4];       // A fragments: W_hh rows g*16 + n, k = q*4+i
    float wih[4][4];      // W_ih[g*16 + q*4 + r]
    float bias[4][4];     // b_ih + b_hh at same rows
    #pragma unroll
    for (int g = 0; g < 4; ++g) {
        const int arow = g * 16 + n;      // A: m = lane&15
        half4 wf;
        #pragma unroll
        for (int i = 0; i < 4; ++i)
            wf[i] = (_Float16)W_hh[arow * 16 + (q * 4 + i)];
        wfrag[g] = wf;
        #pragma unroll
        for (int r = 0; r < 4; ++r) {
            const int row = g * 16 + q * 4 + r;   // D: row = q*4+r
            wih[g][r]  = W_ih[row];
            bias[g][r] = b_ih[row] + b_hh[row];
        }
    }

    half4 hfrag = {(_Float16)0.f, (_Float16)0.f, (_Float16)0.f, (_Float16)0.f};
    float c[4]    = {0.f, 0.f, 0.f, 0.f};
    float hreg[4] = {0.f, 0.f, 0.f, 0.f};

    const float* xp = x + (size_t)(batch0 + n) * TT;   // all 4 quads read same addr (broadcast)

    for (int t4 = 0; t4 < TT; t4 += 4) {
        const float4 xv = *(const float4*)(xp + t4);
        const float xs4[4] = {xv.x, xv.y, xv.z, xv.w};

        #pragma unroll
        for (int s = 0; s < 4; ++s) {
            const float xs = xs4[s];
            f32x4 acc[4];
            #pragma unroll
            for (int g = 0; g < 4; ++g) {
                f32x4 ci;
                #pragma unroll
                for (int r = 0; r < 4; ++r)
                    ci[r] = fmaf(wih[g][r], xs, bias[g][r]);
                acc[g] = __builtin_amdgcn_mfma_f32_16x16x16f16(wfrag[g], hfrag, ci, 0, 0, 0);
            }
            #pragma unroll
            for (int r = 0; r < 4; ++r) {
                const float ig = fast_sigmoid(acc[0][r]);
                const float fg = fast_sigmoid(acc[1][r]);
                const float gg = fast_tanh(acc[2][r]);
                const float og = fast_sigmoid(acc[3][r]);
                c[r] = fmaf(fg, c[r], ig * gg);
                const float hv = og * fast_tanh(c[r]);
                hreg[r] = hv;
                hfrag[r] = (_Float16)hv;
            }
        }
    }

    // ---- head: stage final h (fp32) -> 16 lanes do MLP + log_softmax ----
    float* fh = lds_f[wib];
    #pragma unroll
    for (int r = 0; r < 4; ++r)
        fh[n * 17 + (q * 4 + r)] = hreg[r];   // fh[batch][hid]

    if (lane < 16) {
        const int b = batch0 + lane;
        float hv[16];
        #pragma unroll
        for (int j = 0; j < 16; ++j) hv[j] = fh[lane * 17 + j];

        float a1[32];
        #pragma unroll
        for (int u = 0; u < 32; ++u) {
            float s = b1[u];
            #pragma unroll
            for (int j = 0; j < 16; ++j) s = fmaf(W1[u * 16 + j], hv[j], s);
            a1[u] = fmaxf(s, 0.0f);
        }

        float z[6];
        float m = -1e30f;
        #pragma unroll
        for (int v = 0; v < 6; ++v) {
            float s = b2[v];
            #pragma unroll
            for (int u = 0; u < 32; ++u) s = fmaf(W2[v * 32 + u], a1[u], s);
            z[v] = s;
            m = fmaxf(m, s);
        }
        float se = 0.0f;
        #pragma unroll
        for (int v = 0; v < 6; ++v) se += EXP2F((z[v] - m) * LOG2E);
        const float lse = m + LOG2F(se) * LN2;
        #pragma unroll
        for (int v = 0; v < 6; ++v) out[b * 6 + v] = z[v] - lse;
    }
}

extern "C" void kernel_launch(void* const* d_in, const int* in_sizes, int n_in,
                              void* d_out, int out_size, void* d_ws, size_t ws_size,
                              hipStream_t stream) {
    const float* x    = (const float*)d_in[0];
    const float* W_ih = (const float*)d_in[1];
    const float* W_hh = (const float*)d_in[2];
    const float* b_ih = (const float*)d_in[3];
    const float* b_hh = (const float*)d_in[4];
    const float* W1   = (const float*)d_in[5];
    const float* b1   = (const float*)d_in[6];
    const float* W2   = (const float*)d_in[7];
    const float* b2   = (const float*)d_in[8];
    float* out = (float*)d_out;

    const int B = out_size / 6;          // 32768
    const int nblocks = B / 64;          // 64 batch per block (4 waves x 16)

    hipLaunchKernelGGL(lstm_head_kernel, dim3(nblocks), dim3(256), 0, stream,
                       x, W_ih, W_hh, b_ih, b_hh, W1, b1, W2, b2, out);
}

// Round 3
// 610.302 us; speedup vs baseline: 1.2955x; 1.2064x over previous
//
#include <hip/hip_runtime.h>

#define TT 1024
#define LOG2E 1.4426950408889634f
#define LN2   0.6931471805599453f

typedef __attribute__((ext_vector_type(4))) _Float16 half4;
typedef __attribute__((ext_vector_type(4))) float f32x4;

#if __has_builtin(__builtin_amdgcn_exp2f)
#define EXP2F(x) __builtin_amdgcn_exp2f(x)
#else
#define EXP2F(x) exp2f(x)
#endif
#if __has_builtin(__builtin_amdgcn_logf)
#define LOG2F(x) __builtin_amdgcn_logf(x)
#else
#define LOG2F(x) log2f(x)
#endif

// Gates computed TRANSPOSED via v_mfma_f32_16x16x16f16 (D layout == B layout,
// so updated h feeds the next step's B fragment with 4 cvt ops — no LDS).
//
// Round-3 changes (VALU-issue-bound; cut issued ops):
//  * Gate domain PRE-SCALED: W_hh/W_ih/bias rows for i,f,o scaled by -log2e,
//    g row by +2log2e, so every exponential is exp2(acc) with no input mul.
//  * Cell state kept in scaled domain Cs = 2*log2e*c, so tanh(c)'s exp2 also
//    needs no mul.
//  * Reciprocal merging: c-update uses ONE rcp (common denominator over
//    f,i,g), h uses ONE rcp (common denominator over o and tanh(c)).
//    Per row: 5 exp + 2 rcp (was 5 exp + 5 rcp), 22 instrs (was 26).
__global__ __launch_bounds__(256, 2)
void lstm_head_kernel(const float* __restrict__ x,
                      const float* __restrict__ W_ih,
                      const float* __restrict__ W_hh,
                      const float* __restrict__ b_ih,
                      const float* __restrict__ b_hh,
                      const float* __restrict__ W1,
                      const float* __restrict__ b1,
                      const float* __restrict__ W2,
                      const float* __restrict__ b2,
                      float* __restrict__ out)
{
    __shared__ float lds_f[4][16 * 17];   // final h fp32 staging for the head

    const int tid  = threadIdx.x;
    const int wib  = tid >> 6;
    const int lane = tid & 63;
    const int n    = lane & 15;           // batch within tile (and A-row m)
    const int q    = lane >> 4;           // quadrant
    const int batch0 = (blockIdx.x * 4 + wib) * 16;

    const float KG = 2.0f * LOG2E;        // g-gate / cell-domain scale

    // ---- fixed per-lane constants (pre-scaled into exp2 domain) ----
    half4 wfrag[4];       // A fragments: scaled W_hh rows g*16 + n, k = q*4+i
    float wih[4][4];      // scaled W_ih[g*16 + q*4 + r]
    float bias[4][4];     // scaled (b_ih + b_hh)
    #pragma unroll
    for (int g = 0; g < 4; ++g) {
        const float sc = (g == 2) ? KG : -LOG2E;   // i,f,o -> -log2e; g -> +2log2e
        const int arow = g * 16 + n;               // A: m = lane&15
        half4 wf;
        #pragma unroll
        for (int i = 0; i < 4; ++i)
            wf[i] = (_Float16)(W_hh[arow * 16 + (q * 4 + i)] * sc);
        wfrag[g] = wf;
        #pragma unroll
        for (int r = 0; r < 4; ++r) {
            const int row = g * 16 + q * 4 + r;    // D: row = q*4+r
            wih[g][r]  = W_ih[row] * sc;
            bias[g][r] = (b_ih[row] + b_hh[row]) * sc;
        }
    }

    half4 hfrag = {(_Float16)0.f, (_Float16)0.f, (_Float16)0.f, (_Float16)0.f};
    float Cs[4]   = {0.f, 0.f, 0.f, 0.f};   // scaled cell state: 2*log2e * c
    float hreg[4] = {0.f, 0.f, 0.f, 0.f};

    const float* xp = x + (size_t)(batch0 + n) * TT;   // quads read same addr (broadcast)

    for (int t4 = 0; t4 < TT; t4 += 4) {
        const float4 xv = *(const float4*)(xp + t4);
        const float xs4[4] = {xv.x, xv.y, xv.z, xv.w};

        #pragma unroll
        for (int s = 0; s < 4; ++s) {
            const float xs = xs4[s];
            f32x4 acc[4];
            #pragma unroll
            for (int g = 0; g < 4; ++g) {
                f32x4 ci;
                #pragma unroll
                for (int r = 0; r < 4; ++r)
                    ci[r] = fmaf(wih[g][r], xs, bias[g][r]);
                acc[g] = __builtin_amdgcn_mfma_f32_16x16x16f16(wfrag[g], hfrag, ci, 0, 0, 0);
            }
            #pragma unroll
            for (int r = 0; r < 4; ++r) {
                // ei=e^{-ai}, ef=e^{-af}, eg=e^{2ag}, eo=e^{-ao}
                const float ei = EXP2F(acc[0][r]);
                const float ef = EXP2F(acc[1][r]);
                const float eg = EXP2F(acc[2][r]);
                const float eo = EXP2F(acc[3][r]);
                // c' = c/(1+ef) + (eg-1)/((1+ei)(eg+1))  [scaled by KG]
                const float pei = ei + 1.0f;
                const float pef = ef + 1.0f;
                const float egp = eg + 1.0f;
                const float egm = fmaf(KG, eg, -KG);        // KG*(eg-1)
                const float P   = pei * egp;
                const float D   = pef * P;
                const float t2  = pef * egm;
                const float num = fmaf(Cs[r], P, t2);
                const float Cn  = num * __builtin_amdgcn_rcpf(D);
                Cs[r] = Cn;
                // h = (ec-1)/((1+eo)(ec+1)),  ec = e^{2c} = exp2(Cn)
                const float ec  = EXP2F(Cn);
                const float peo = eo + 1.0f;
                const float ecp = ec + 1.0f;
                const float ecm = ec - 1.0f;
                const float D2  = peo * ecp;
                const float hv  = ecm * __builtin_amdgcn_rcpf(D2);
                hreg[r] = hv;
                hfrag[r] = (_Float16)hv;
            }
        }
    }

    // ---- head: stage final h (fp32) -> 16 lanes do MLP + log_softmax ----
    float* fh = lds_f[wib];
    #pragma unroll
    for (int r = 0; r < 4; ++r)
        fh[n * 17 + (q * 4 + r)] = hreg[r];   // fh[batch][hid]

    if (lane < 16) {
        const int b = batch0 + lane;
        float hv[16];
        #pragma unroll
        for (int j = 0; j < 16; ++j) hv[j] = fh[lane * 17 + j];

        float a1[32];
        #pragma unroll
        for (int u = 0; u < 32; ++u) {
            float s = b1[u];
            #pragma unroll
            for (int j = 0; j < 16; ++j) s = fmaf(W1[u * 16 + j], hv[j], s);
            a1[u] = fmaxf(s, 0.0f);
        }

        float z[6];
        float m = -1e30f;
        #pragma unroll
        for (int v = 0; v < 6; ++v) {
            float s = b2[v];
            #pragma unroll
            for (int u = 0; u < 32; ++u) s = fmaf(W2[v * 32 + u], a1[u], s);
            z[v] = s;
            m = fmaxf(m, s);
        }
        float se = 0.0f;
        #pragma unroll
        for (int v = 0; v < 6; ++v) se += EXP2F((z[v] - m) * LOG2E);
        const float lse = m + LOG2F(se) * LN2;
        #pragma unroll
        for (int v = 0; v < 6; ++v) out[b * 6 + v] = z[v] - lse;
    }
}

extern "C" void kernel_launch(void* const* d_in, const int* in_sizes, int n_in,
                              void* d_out, int out_size, void* d_ws, size_t ws_size,
                              hipStream_t stream) {
    const float* x    = (const float*)d_in[0];
    const float* W_ih = (const float*)d_in[1];
    const float* W_hh = (const float*)d_in[2];
    const float* b_ih = (const float*)d_in[3];
    const float* b_hh = (const float*)d_in[4];
    const float* W1   = (const float*)d_in[5];
    const float* b1   = (const float*)d_in[6];
    const float* W2   = (const float*)d_in[7];
    const float* b2   = (const float*)d_in[8];
    float* out = (float*)d_out;

    const int B = out_size / 6;          // 32768
    const int nblocks = B / 64;          // 64 batch per block (4 waves x 16)

    hipLaunchKernelGGL(lstm_head_kernel, dim3(nblocks), dim3(256), 0, stream,
                       x, W_ih, W_hh, b_ih, b_hh, W1, b1, W2, b2, out);
}

// Round 5
// 592.451 us; speedup vs baseline: 1.3346x; 1.0301x over previous
//
#include <hip/hip_runtime.h>

#define TT 1024
#define LOG2E 1.4426950408889634f
#define LN2   0.6931471805599453f

typedef __attribute__((ext_vector_type(2))) float f32x2;
typedef __attribute__((ext_vector_type(4))) float f32x4;
typedef __attribute__((ext_vector_type(2))) _Float16 half2_t;
typedef __attribute__((ext_vector_type(4))) _Float16 half4;
typedef __attribute__((ext_vector_type(2))) __fp16 fp16x2_raw;

#if __has_builtin(__builtin_amdgcn_exp2f)
#define EXP2F(x) __builtin_amdgcn_exp2f(x)
#else
#define EXP2F(x) exp2f(x)
#endif
#if __has_builtin(__builtin_amdgcn_logf)
#define LOG2F(x) __builtin_amdgcn_logf(x)
#else
#define LOG2F(x) log2f(x)
#endif
#define RCPF(x) __builtin_amdgcn_rcpf(x)

// Gates computed TRANSPOSED via v_mfma_f32_16x16x16f16 (D layout == B layout:
// updated h feeds the next step's B fragment directly — no LDS in recurrence).
// Gate domain pre-scaled into exp2 space; merged reciprocals (5 exp + 2 rcp
// per row, the algebraic minimum).
//
// Round-4/5 change (VALU-issue-bound, VALUBusy 78%): PACK all full-rate
// fp32 math pairwise over independent rows (0,1) and (2,3) as <2 x float>
// ext-vectors so the backend selects v_pk_{add,mul,fma}_f32 (VOP3P dual-lane
// fp32). Transcendentals stay scalar (no packed trans pipe). f16 h-convert
// via v_cvt_pkrtz (2-in-1). Halves the non-transcendental issue stream.
__global__ __launch_bounds__(256, 2)
void lstm_head_kernel(const float* __restrict__ x,
                      const float* __restrict__ W_ih,
                      const float* __restrict__ W_hh,
                      const float* __restrict__ b_ih,
                      const float* __restrict__ b_hh,
                      const float* __restrict__ W1,
                      const float* __restrict__ b1,
                      const float* __restrict__ W2,
                      const float* __restrict__ b2,
                      float* __restrict__ out)
{
    __shared__ float lds_f[4][16 * 17];   // final h fp32 staging for the head

    const int tid  = threadIdx.x;
    const int wib  = tid >> 6;
    const int lane = tid & 63;
    const int n    = lane & 15;           // batch within tile (and A-row m)
    const int q    = lane >> 4;           // quadrant
    const int batch0 = (blockIdx.x * 4 + wib) * 16;

    const float KG = 2.0f * LOG2E;        // g-gate / cell-domain scale

    // ---- fixed per-lane constants (pre-scaled into exp2 domain) ----
    half4 wfrag[4];        // A fragments: scaled W_hh rows g*16 + n, k = q*4+i
    f32x2 wih[4][2];       // scaled W_ih, row-pairs (r0,r1) / (r2,r3)
    f32x2 bias[4][2];      // scaled (b_ih + b_hh)
    #pragma unroll
    for (int g = 0; g < 4; ++g) {
        const float sc = (g == 2) ? KG : -LOG2E;   // i,f,o -> -log2e; g -> +2log2e
        const int arow = g * 16 + n;               // A: m = lane&15
        half4 wf;
        #pragma unroll
        for (int i = 0; i < 4; ++i)
            wf[i] = (_Float16)(W_hh[arow * 16 + (q * 4 + i)] * sc);
        wfrag[g] = wf;
        #pragma unroll
        for (int p = 0; p < 2; ++p) {
            const int row0 = g * 16 + q * 4 + 2 * p;
            wih[g][p]  = (f32x2){W_ih[row0] * sc, W_ih[row0 + 1] * sc};
            bias[g][p] = (f32x2){(b_ih[row0] + b_hh[row0]) * sc,
                                 (b_ih[row0 + 1] + b_hh[row0 + 1]) * sc};
        }
    }

    half4 hfrag = {(_Float16)0.f, (_Float16)0.f, (_Float16)0.f, (_Float16)0.f};
    f32x2 Cs[2] = {(f32x2){0.f, 0.f}, (f32x2){0.f, 0.f}};   // scaled cell state
    f32x2 hv[2] = {(f32x2){0.f, 0.f}, (f32x2){0.f, 0.f}};   // last h (fp32)

    const float* xp = x + (size_t)(batch0 + n) * TT;   // quads read same addr (broadcast)

    for (int t4 = 0; t4 < TT; t4 += 4) {
        const float4 xv = *(const float4*)(xp + t4);
        const float xs4[4] = {xv.x, xv.y, xv.z, xv.w};

        #pragma unroll
        for (int s = 0; s < 4; ++s) {
            const float xs = xs4[s];
            f32x4 acc[4];
            #pragma unroll
            for (int g = 0; g < 4; ++g) {
                const f32x2 ci0 = __builtin_elementwise_fma(wih[g][0], (f32x2)xs, bias[g][0]);
                const f32x2 ci1 = __builtin_elementwise_fma(wih[g][1], (f32x2)xs, bias[g][1]);
                const f32x4 ci = {ci0.x, ci0.y, ci1.x, ci1.y};
                acc[g] = __builtin_amdgcn_mfma_f32_16x16x16f16(wfrag[g], hfrag, ci, 0, 0, 0);
            }

            half2_t hh[2];
            #pragma unroll
            for (int p = 0; p < 2; ++p) {
                const f32x2 ai = {acc[0][2*p], acc[0][2*p + 1]};
                const f32x2 af = {acc[1][2*p], acc[1][2*p + 1]};
                const f32x2 ag = {acc[2][2*p], acc[2][2*p + 1]};
                const f32x2 ao = {acc[3][2*p], acc[3][2*p + 1]};

                const f32x2 ei = {EXP2F(ai.x), EXP2F(ai.y)};
                const f32x2 ef = {EXP2F(af.x), EXP2F(af.y)};
                const f32x2 eg = {EXP2F(ag.x), EXP2F(ag.y)};
                const f32x2 eo = {EXP2F(ao.x), EXP2F(ao.y)};

                // c' = c/(1+ef) + (eg-1)/((1+ei)(eg+1))  [scaled by KG]
                const f32x2 pei = ei + 1.0f;
                const f32x2 pef = ef + 1.0f;
                const f32x2 egp = eg + 1.0f;
                const f32x2 egm = __builtin_elementwise_fma((f32x2)KG, eg, (f32x2)(-KG));
                const f32x2 P   = pei * egp;
                const f32x2 D   = pef * P;
                const f32x2 t2  = pef * egm;
                const f32x2 num = __builtin_elementwise_fma(Cs[p], P, t2);
                const f32x2 rD  = {RCPF(D.x), RCPF(D.y)};
                const f32x2 Cn  = num * rD;
                Cs[p] = Cn;

                // h = (ec-1)/((1+eo)(ec+1)),  ec = exp2(Cn)
                const f32x2 ec  = {EXP2F(Cn.x), EXP2F(Cn.y)};
                const f32x2 peo = eo + 1.0f;
                const f32x2 ecp = ec + 1.0f;
                const f32x2 ecm = ec - 1.0f;
                const f32x2 D2  = peo * ecp;
                const f32x2 rD2 = {RCPF(D2.x), RCPF(D2.y)};
                const f32x2 h2  = ecm * rD2;
                hv[p] = h2;
                hh[p] = __builtin_bit_cast(half2_t, __builtin_amdgcn_cvt_pkrtz(h2.x, h2.y));
            }
            hfrag = (half4){hh[0].x, hh[0].y, hh[1].x, hh[1].y};
        }
    }

    // ---- head: stage final h (fp32) -> 16 lanes do MLP + log_softmax ----
    float* fh = lds_f[wib];
    #pragma unroll
    for (int p = 0; p < 2; ++p) {
        fh[n * 17 + (q * 4 + 2*p)]     = hv[p].x;
        fh[n * 17 + (q * 4 + 2*p + 1)] = hv[p].y;
    }

    if (lane < 16) {
        const int b = batch0 + lane;
        float hvv[16];
        #pragma unroll
        for (int j = 0; j < 16; ++j) hvv[j] = fh[lane * 17 + j];

        float a1[32];
        #pragma unroll
        for (int u = 0; u < 32; ++u) {
            float s = b1[u];
            #pragma unroll
            for (int j = 0; j < 16; ++j) s = fmaf(W1[u * 16 + j], hvv[j], s);
            a1[u] = fmaxf(s, 0.0f);
        }

        float z[6];
        float m = -1e30f;
        #pragma unroll
        for (int v = 0; v < 6; ++v) {
            float s = b2[v];
            #pragma unroll
            for (int u = 0; u < 32; ++u) s = fmaf(W2[v * 32 + u], a1[u], s);
            z[v] = s;
            m = fmaxf(m, s);
        }
        float se = 0.0f;
        #pragma unroll
        for (int v = 0; v < 6; ++v) se += EXP2F((z[v] - m) * LOG2E);
        const float lse = m + LOG2F(se) * LN2;
        #pragma unroll
        for (int v = 0; v < 6; ++v) out[b * 6 + v] = z[v] - lse;
    }
}

extern "C" void kernel_launch(void* const* d_in, const int* in_sizes, int n_in,
                              void* d_out, int out_size, void* d_ws, size_t ws_size,
                              hipStream_t stream) {
    const float* x    = (const float*)d_in[0];
    const float* W_ih = (const float*)d_in[1];
    const float* W_hh = (const float*)d_in[2];
    const float* b_ih = (const float*)d_in[3];
    const float* b_hh = (const float*)d_in[4];
    const float* W1   = (const float*)d_in[5];
    const float* b1   = (const float*)d_in[6];
    const float* W2   = (const float*)d_in[7];
    const float* b2   = (const float*)d_in[8];
    float* out = (float*)d_out;

    const int B = out_size / 6;          // 32768
    const int nblocks = B / 64;          // 64 batch per block (4 waves x 16)

    hipLaunchKernelGGL(lstm_head_kernel, dim3(nblocks), dim3(256), 0, stream,
                       x, W_ih, W_hh, b_ih, b_hh, W1, b1, W2, b2, out);
}